// Round 2
// baseline (28268.643 us; speedup 1.0000x reference)
//
#include <hip/hip_runtime.h>

#define TT 500
#define NB_BATCH 64
#define HID 1024
#define NC 2048   // 2*HID (z-gate cols 0..1023, h-gate cols 1024..2047)

typedef __attribute__((ext_vector_type(8))) __bf16 bf16x8;
typedef __attribute__((ext_vector_type(8))) unsigned short us8;
typedef __attribute__((ext_vector_type(4))) unsigned short us4;
typedef __attribute__((ext_vector_type(4))) float f32x4;

__device__ __forceinline__ unsigned short f2bf(float f) {
  unsigned u = __builtin_bit_cast(unsigned, f);
  u += 0x7fffu + ((u >> 16) & 1u);
  return (unsigned short)(u >> 16);
}
__device__ __forceinline__ float bf2f(unsigned short h) {
  unsigned u = ((unsigned)h) << 16;
  return __builtin_bit_cast(float, u);
}
__device__ __forceinline__ bf16x8 ld_bf8(const unsigned short* p) {
  return __builtin_bit_cast(bf16x8, *(const us8*)p);
}

// ---------------------------------------------------------------------------
// Kernel 1: fused input projection + BatchNorm.  (unchanged from R1 — passing)
// ---------------------------------------------------------------------------
#define XS_STR 40
#define WS_STR 40

__global__ __launch_bounds__(256) void proj_bn_kernel(
    const float* __restrict__ X, int K,
    const float* __restrict__ Wxz, const float* __restrict__ Wxh,
    const float* __restrict__ gz, const float* __restrict__ bz,
    const float* __restrict__ gh, const float* __restrict__ bh,
    unsigned short* __restrict__ A)
{
  __shared__ unsigned short Xs[64 * XS_STR];
  __shared__ unsigned short Ws[128 * WS_STR];

  const int t   = blockIdx.x >> 4;
  const int nt  = blockIdx.x & 15;
  const int tid = threadIdx.x;
  const int wave = tid >> 6;
  const int lane = tid & 63;
  const int lm = lane & 15;
  const int lq = lane >> 4;

  const float* Wsrc = (nt < 8) ? (Wxz + (size_t)(nt * 128) * K)
                               : (Wxh + (size_t)((nt - 8) * 128) * K);
  const float* Xbase = X + (size_t)(t * 64) * K;

  f32x4 acc[4][2];
#pragma unroll
  for (int i = 0; i < 4; i++)
#pragma unroll
    for (int j = 0; j < 2; j++) acc[i][j] = (f32x4){0.f, 0.f, 0.f, 0.f};

  const int nkt = K >> 5;
  for (int kt = 0; kt < nkt; ++kt) {
    const int k0 = kt << 5;
#pragma unroll
    for (int it = 0; it < 2; ++it) {
      int idx = it * 256 + tid;
      int r = idx >> 3, c4 = idx & 7;
      float4 v = *(const float4*)(Xbase + (size_t)r * K + k0 + c4 * 4);
      us4 o; o[0] = f2bf(v.x); o[1] = f2bf(v.y); o[2] = f2bf(v.z); o[3] = f2bf(v.w);
      *(us4*)&Xs[r * XS_STR + c4 * 4] = o;
    }
#pragma unroll
    for (int it = 0; it < 4; ++it) {
      int idx = it * 256 + tid;
      int r = idx >> 3, c4 = idx & 7;
      float4 v = *(const float4*)(Wsrc + (size_t)r * K + k0 + c4 * 4);
      us4 o; o[0] = f2bf(v.x); o[1] = f2bf(v.y); o[2] = f2bf(v.z); o[3] = f2bf(v.w);
      *(us4*)&Ws[r * WS_STR + c4 * 4] = o;
    }
    __syncthreads();
    bf16x8 bfr0 = ld_bf8(&Ws[(wave * 32 + lm) * WS_STR + lq * 8]);
    bf16x8 bfr1 = ld_bf8(&Ws[(wave * 32 + 16 + lm) * WS_STR + lq * 8]);
#pragma unroll
    for (int rt = 0; rt < 4; ++rt) {
      bf16x8 afr = ld_bf8(&Xs[(rt * 16 + lm) * XS_STR + lq * 8]);
      acc[rt][0] = __builtin_amdgcn_mfma_f32_16x16x32_bf16(afr, bfr0, acc[rt][0], 0, 0, 0);
      acc[rt][1] = __builtin_amdgcn_mfma_f32_16x16x32_bf16(afr, bfr1, acc[rt][1], 0, 0, 0);
    }
    __syncthreads();
  }

  const float inv64 = 1.0f / 64.0f;
#pragma unroll
  for (int ct = 0; ct < 2; ++ct) {
    float s1 = 0.f, s2 = 0.f;
#pragma unroll
    for (int rt = 0; rt < 4; ++rt)
#pragma unroll
      for (int r = 0; r < 4; ++r) {
        float v = acc[rt][ct][r];
        s1 += v; s2 += v * v;
      }
    s1 += __shfl_xor(s1, 16, 64); s2 += __shfl_xor(s2, 16, 64);
    s1 += __shfl_xor(s1, 32, 64); s2 += __shfl_xor(s2, 32, 64);
    float mean = s1 * inv64;
    float var  = s2 * inv64 - mean * mean;
    int col = nt * 128 + wave * 32 + ct * 16 + lm;
    float g, be;
    if (col < 1024) { g = gz[col];        be = bz[col]; }
    else            { g = gh[col - 1024]; be = bh[col - 1024]; }
    float scale = g * rsqrtf(var + 1e-5f);
    float shift = be - mean * scale;
    unsigned short* Aout = A + (size_t)(t * 64) * NC + col;
#pragma unroll
    for (int rt = 0; rt < 4; ++rt)
#pragma unroll
      for (int r = 0; r < 4; ++r) {
        int b = rt * 16 + lq * 4 + r;
        Aout[(size_t)b * NC] = f2bf(acc[rt][ct][r] * scale + shift);
      }
  }
}

// ---------------------------------------------------------------------------
// Kernel 2: persistent cooperative scan.
// R2 change: replace the single contended atomic-counter grid barrier
// (256 serialized device-scope RMWs/step ~ 25us) with 4 INDEPENDENT
// per-batch-group barriers (64 blocks each), flag-array + aggregator:
//   - each block release-stores its epoch to its own 64B-padded flag
//   - the group's fg==0 block polls 64 flags (1 flag per lane), then
//     release-stores go[bg]
//   - other blocks poll go[bg] (read-only, no RMW contention)
// Dependency argument: block (bg,fg) writes h rows [bg*16,+16) only and
// reads h rows [bg*16,+16) only -> same-bg blocks form a closed group.
// ---------------------------------------------------------------------------
__global__ __launch_bounds__(64) void scan_kernel(
    const unsigned short* __restrict__ A,   // [T][64][2048] bf16
    const float* __restrict__ Whz, const float* __restrict__ bhz,
    const float* __restrict__ Whh, const float* __restrict__ bhh,
    unsigned short* __restrict__ hbuf,      // [2][64][1024] bf16
    float* __restrict__ ys,                 // [T][64][1024] fp32
    unsigned* __restrict__ flags,           // 256 x 16 uints (64B padded)
    unsigned* __restrict__ go)              // 4 x 16 uints (64B padded)
{
  extern __shared__ unsigned short Wlds[];  // 2 * 16 * 1024 bf16 = 64 KB
  const int lane = threadIdx.x;
  const int fg = blockIdx.x & 63;
  const int bg = blockIdx.x >> 6;
  const int lm = lane & 15;
  const int lq = lane >> 4;
  const int jg = fg * 16 + lm;   // this lane's feature column

  // Stage both weight slices (fp32 -> bf16), rotated-chunk layout:
  // elem off = g*16384 + r*1024 + ((c + 5*r)&127)*8 + half*4
  for (int g = 0; g < 2; ++g) {
    const float* Wsrc = (g ? Whh : Whz) + (size_t)(fg * 16) * HID;
#pragma unroll 4
    for (int it = 0; it < 64; ++it) {
      int idx = it * 64 + lane;          // 0..4095
      int r = idx >> 8, c4 = idx & 255;  // row, float4 index
      float4 v = *(const float4*)(Wsrc + (size_t)r * HID + c4 * 4);
      int c = c4 >> 1, hh = c4 & 1;
      us4 o; o[0] = f2bf(v.x); o[1] = f2bf(v.y); o[2] = f2bf(v.z); o[3] = f2bf(v.w);
      *(us4*)&Wlds[g * 16384 + r * 1024 + (((c + 5 * r) & 127) << 3) + hh * 4] = o;
    }
  }
  const float bzv = bhz[jg];
  const float bhv = bhh[jg];
  __syncthreads();

  // prefetch az/ah for t=0 (lane owns rows b = bg*16 + lq*4 + r, col jg)
  unsigned short aznx[4], ahnx[4];
  {
    const unsigned short* p = A + (size_t)(bg * 16 + lq * 4) * NC + jg;
#pragma unroll
    for (int r = 0; r < 4; ++r) { aznx[r] = p[(size_t)r * NC]; ahnx[r] = p[(size_t)r * NC + 1024]; }
  }
  float h_own[4] = {0.f, 0.f, 0.f, 0.f};

  unsigned* myflag  = &flags[blockIdx.x * 16];
  unsigned* pollflag = &flags[(bg * 64 + lane) * 16];
  unsigned* goword  = &go[bg * 16];

  for (int t = 0; t < TT; ++t) {
    f32x4 accz = {0.f, 0.f, 0.f, 0.f}, acch = {0.f, 0.f, 0.f, 0.f};
    if (t > 0) {
      const unsigned short* hsrc = hbuf + (size_t)(t & 1) * 65536 + (size_t)(bg * 16 + lm) * HID;
#pragma unroll 8
      for (int kt = 0; kt < 32; ++kt) {
        bf16x8 afr = ld_bf8(hsrc + kt * 32 + lq * 8);
        int c = ((kt * 4 + lq) + 5 * lm) & 127;
        bf16x8 bz8 = ld_bf8(&Wlds[lm * 1024 + c * 8]);
        bf16x8 bh8 = ld_bf8(&Wlds[16384 + lm * 1024 + c * 8]);
        accz = __builtin_amdgcn_mfma_f32_16x16x32_bf16(afr, bz8, accz, 0, 0, 0);
        acch = __builtin_amdgcn_mfma_f32_16x16x32_bf16(afr, bh8, acch, 0, 0, 0);
      }
    }
    unsigned short azc[4], ahc[4];
#pragma unroll
    for (int r = 0; r < 4; ++r) { azc[r] = aznx[r]; ahc[r] = ahnx[r]; }
    if (t + 1 < TT) {
      const unsigned short* p = A + ((size_t)(t + 1) * 64 + bg * 16 + lq * 4) * NC + jg;
#pragma unroll
      for (int r = 0; r < 4; ++r) { aznx[r] = p[(size_t)r * NC]; ahnx[r] = p[(size_t)r * NC + 1024]; }
    }
    float* ysp = ys + ((size_t)t * 64 + bg * 16 + lq * 4) * HID + jg;
    unsigned short* hnp = hbuf + (size_t)((t + 1) & 1) * 65536 + (size_t)(bg * 16 + lq * 4) * HID + jg;
#pragma unroll
    for (int r = 0; r < 4; ++r) {
      float z  = 1.0f / (1.0f + __expf(-(bf2f(azc[r]) + accz[r] + bzv)));
      float ht = bf2f(ahc[r]) + acch[r] + bhv;
      ht = ht > 0.f ? ht : 0.f;
      float h2 = z * h_own[r] + (1.0f - z) * ht;
      h_own[r] = h2;
      ysp[(size_t)r * HID] = h2;
      hnp[(size_t)r * HID] = f2bf(h2);
    }

    // ---- per-bg-group barrier (64 blocks), flag + aggregator ----
    const unsigned next = (unsigned)(t + 1);
    __threadfence();   // drain h stores before signaling
    if (lane == 0)
      __hip_atomic_store(myflag, next, __ATOMIC_RELEASE, __HIP_MEMORY_SCOPE_AGENT);
    if (fg == 0) {
      // aggregator: lane L waits for block bg*64+L (incl. own flag)
      while (__hip_atomic_load(pollflag, __ATOMIC_ACQUIRE, __HIP_MEMORY_SCOPE_AGENT) < next)
        __builtin_amdgcn_s_sleep(1);
      __syncthreads();
      if (lane == 0)
        __hip_atomic_store(goword, next, __ATOMIC_RELEASE, __HIP_MEMORY_SCOPE_AGENT);
    } else {
      if (lane == 0) {
        while (__hip_atomic_load(goword, __ATOMIC_ACQUIRE, __HIP_MEMORY_SCOPE_AGENT) < next)
          __builtin_amdgcn_s_sleep(1);
      }
      __syncthreads();
    }
    __threadfence();   // acquire side for all lanes (L1 invalidate)
  }
}

// ---------------------------------------------------------------------------
extern "C" void kernel_launch(void* const* d_in, const int* in_sizes, int n_in,
                              void* d_out, int out_size, void* d_ws, size_t ws_size,
                              hipStream_t stream)
{
  (void)in_sizes; (void)n_in; (void)out_size; (void)ws_size;
  const float* x    = (const float*)d_in[0];
  const float* Wxz0 = (const float*)d_in[1];
  const float* gz0  = (const float*)d_in[3];
  const float* bz0  = (const float*)d_in[4];
  const float* Whz0 = (const float*)d_in[5];
  const float* bhz0 = (const float*)d_in[6];
  const float* Wxh0 = (const float*)d_in[7];
  const float* gh0  = (const float*)d_in[9];
  const float* bh0  = (const float*)d_in[10];
  const float* Whh0 = (const float*)d_in[11];
  const float* bhh0 = (const float*)d_in[12];
  const float* Wxz1 = (const float*)d_in[13];
  const float* gz1  = (const float*)d_in[15];
  const float* bz1  = (const float*)d_in[16];
  const float* Whz1 = (const float*)d_in[17];
  const float* bhz1 = (const float*)d_in[18];
  const float* Wxh1 = (const float*)d_in[19];
  const float* gh1  = (const float*)d_in[21];
  const float* bh1  = (const float*)d_in[22];
  const float* Whh1 = (const float*)d_in[23];
  const float* bhh1 = (const float*)d_in[24];

  char* ws = (char*)d_ws;
  // barrier region: [0,64KB): layer0 flags @0 (16KB), go0 @16384 (256B),
  //                 layer1 flags @32768, go1 @49152
  unsigned* flags0 = (unsigned*)(ws);
  unsigned* go0    = (unsigned*)(ws + 16384);
  unsigned* flags1 = (unsigned*)(ws + 32768);
  unsigned* go1    = (unsigned*)(ws + 49152);
  unsigned short* hbuf = (unsigned short*)(ws + 65536);          // 256 KB
  unsigned short* A    = (unsigned short*)(ws + (1 << 19));      // 131 MB
  float* ys0 = (float*)(ws + (1 << 19) + (size_t)TT * 64 * NC * 2); // 131 MB
  float* out = (float*)d_out;

  hipMemsetAsync(ws, 0, 65536, stream);

  // ---- layer 0 ----
  proj_bn_kernel<<<dim3(8000), dim3(256), 0, stream>>>(
      x, 512, Wxz0, Wxh0, gz0, bz0, gh0, bh0, A);
  {
    const unsigned short* a0 = A;
    const float* whz = Whz0; const float* vbz = bhz0;
    const float* whh = Whh0; const float* vbh = bhh0;
    unsigned short* hb = hbuf; float* yy = ys0;
    unsigned* ff = flags0; unsigned* gg = go0;
    void* kargs[9] = {&a0, &whz, &vbz, &whh, &vbh, &hb, &yy, &ff, &gg};
    hipLaunchCooperativeKernel((const void*)scan_kernel, dim3(256), dim3(64),
                               kargs, 65536, stream);
  }
  // ---- layer 1 ----
  proj_bn_kernel<<<dim3(8000), dim3(256), 0, stream>>>(
      ys0, 1024, Wxz1, Wxh1, gz1, bz1, gh1, bh1, A);
  {
    const unsigned short* a0 = A;
    const float* whz = Whz1; const float* vbz = bhz1;
    const float* whh = Whh1; const float* vbh = bhh1;
    unsigned short* hb = hbuf; float* yy = out;
    unsigned* ff = flags1; unsigned* gg = go1;
    void* kargs[9] = {&a0, &whz, &vbz, &whh, &vbh, &hb, &yy, &ff, &gg};
    hipLaunchCooperativeKernel((const void*)scan_kernel, dim3(256), dim3(64),
                               kargs, 65536, stream);
  }
}

// Round 3
// 5217.403 us; speedup vs baseline: 5.4181x; 5.4181x over previous
//
#include <hip/hip_runtime.h>

#define TT 500
#define NB_BATCH 64
#define HID 1024
#define NC 2048   // 2*HID (z-gate cols 0..1023, h-gate cols 1024..2047)

typedef __attribute__((ext_vector_type(8))) __bf16 bf16x8;
typedef __attribute__((ext_vector_type(8))) unsigned short us8;
typedef __attribute__((ext_vector_type(4))) unsigned short us4;
typedef __attribute__((ext_vector_type(4))) float f32x4;
typedef __attribute__((ext_vector_type(2))) unsigned long long u64x2;

__device__ __forceinline__ unsigned short f2bf(float f) {
  unsigned u = __builtin_bit_cast(unsigned, f);
  u += 0x7fffu + ((u >> 16) & 1u);
  return (unsigned short)(u >> 16);
}
__device__ __forceinline__ float bf2f(unsigned short h) {
  unsigned u = ((unsigned)h) << 16;
  return __builtin_bit_cast(float, u);
}
__device__ __forceinline__ bf16x8 ld_bf8(const unsigned short* p) {
  return __builtin_bit_cast(bf16x8, *(const us8*)p);
}

// ---------------------------------------------------------------------------
// Kernel 1: fused input projection + BatchNorm.  (unchanged — passing)
// ---------------------------------------------------------------------------
#define XS_STR 40
#define WS_STR 40

__global__ __launch_bounds__(256) void proj_bn_kernel(
    const float* __restrict__ X, int K,
    const float* __restrict__ Wxz, const float* __restrict__ Wxh,
    const float* __restrict__ gz, const float* __restrict__ bz,
    const float* __restrict__ gh, const float* __restrict__ bh,
    unsigned short* __restrict__ A)
{
  __shared__ unsigned short Xs[64 * XS_STR];
  __shared__ unsigned short Ws[128 * WS_STR];

  const int t   = blockIdx.x >> 4;
  const int nt  = blockIdx.x & 15;
  const int tid = threadIdx.x;
  const int wave = tid >> 6;
  const int lane = tid & 63;
  const int lm = lane & 15;
  const int lq = lane >> 4;

  const float* Wsrc = (nt < 8) ? (Wxz + (size_t)(nt * 128) * K)
                               : (Wxh + (size_t)((nt - 8) * 128) * K);
  const float* Xbase = X + (size_t)(t * 64) * K;

  f32x4 acc[4][2];
#pragma unroll
  for (int i = 0; i < 4; i++)
#pragma unroll
    for (int j = 0; j < 2; j++) acc[i][j] = (f32x4){0.f, 0.f, 0.f, 0.f};

  const int nkt = K >> 5;
  for (int kt = 0; kt < nkt; ++kt) {
    const int k0 = kt << 5;
#pragma unroll
    for (int it = 0; it < 2; ++it) {
      int idx = it * 256 + tid;
      int r = idx >> 3, c4 = idx & 7;
      float4 v = *(const float4*)(Xbase + (size_t)r * K + k0 + c4 * 4);
      us4 o; o[0] = f2bf(v.x); o[1] = f2bf(v.y); o[2] = f2bf(v.z); o[3] = f2bf(v.w);
      *(us4*)&Xs[r * XS_STR + c4 * 4] = o;
    }
#pragma unroll
    for (int it = 0; it < 4; ++it) {
      int idx = it * 256 + tid;
      int r = idx >> 3, c4 = idx & 7;
      float4 v = *(const float4*)(Wsrc + (size_t)r * K + k0 + c4 * 4);
      us4 o; o[0] = f2bf(v.x); o[1] = f2bf(v.y); o[2] = f2bf(v.z); o[3] = f2bf(v.w);
      *(us4*)&Ws[r * WS_STR + c4 * 4] = o;
    }
    __syncthreads();
    bf16x8 bfr0 = ld_bf8(&Ws[(wave * 32 + lm) * WS_STR + lq * 8]);
    bf16x8 bfr1 = ld_bf8(&Ws[(wave * 32 + 16 + lm) * WS_STR + lq * 8]);
#pragma unroll
    for (int rt = 0; rt < 4; ++rt) {
      bf16x8 afr = ld_bf8(&Xs[(rt * 16 + lm) * XS_STR + lq * 8]);
      acc[rt][0] = __builtin_amdgcn_mfma_f32_16x16x32_bf16(afr, bfr0, acc[rt][0], 0, 0, 0);
      acc[rt][1] = __builtin_amdgcn_mfma_f32_16x16x32_bf16(afr, bfr1, acc[rt][1], 0, 0, 0);
    }
    __syncthreads();
  }

  const float inv64 = 1.0f / 64.0f;
#pragma unroll
  for (int ct = 0; ct < 2; ++ct) {
    float s1 = 0.f, s2 = 0.f;
#pragma unroll
    for (int rt = 0; rt < 4; ++rt)
#pragma unroll
      for (int r = 0; r < 4; ++r) {
        float v = acc[rt][ct][r];
        s1 += v; s2 += v * v;
      }
    s1 += __shfl_xor(s1, 16, 64); s2 += __shfl_xor(s2, 16, 64);
    s1 += __shfl_xor(s1, 32, 64); s2 += __shfl_xor(s2, 32, 64);
    float mean = s1 * inv64;
    float var  = s2 * inv64 - mean * mean;
    int col = nt * 128 + wave * 32 + ct * 16 + lm;
    float g, be;
    if (col < 1024) { g = gz[col];        be = bz[col]; }
    else            { g = gh[col - 1024]; be = bh[col - 1024]; }
    float scale = g * rsqrtf(var + 1e-5f);
    float shift = be - mean * scale;
    unsigned short* Aout = A + (size_t)(t * 64) * NC + col;
#pragma unroll
    for (int rt = 0; rt < 4; ++rt)
#pragma unroll
      for (int r = 0; r < 4; ++r) {
        int b = rt * 16 + lq * 4 + r;
        Aout[(size_t)b * NC] = f2bf(acc[rt][ct][r] * scale + shift);
      }
  }
}

// ---------------------------------------------------------------------------
// Kernel 2: persistent scan.
// R3: NO cache-maintenance ops anywhere in the step loop (R1/R2's ~26us/step
// was agent-scope acquire/release emitting buffer_inv/buffer_wbl2 L2 flushes
// every poll iteration). All cross-block traffic (h, flags) uses RELAXED
// agent-scope atomics only (device-coherent sc1 accesses, no fences):
//   write h:  shfl-pair pack -> 4B relaxed-agent stores
//   order:    s_waitcnt(0) (store-ack at coherence point) -> relaxed flag
//   poll:     each lane watches one of the group's 64 flags, relaxed loads
//   read h:   64x 8B relaxed-agent loads issued up-front into registers
// ys stores moved after the flag store (off critical path).
// ---------------------------------------------------------------------------
__global__ __launch_bounds__(64) void scan_kernel(
    const unsigned short* __restrict__ A,   // [T][64][2048] bf16
    const float* __restrict__ Whz, const float* __restrict__ bhz,
    const float* __restrict__ Whh, const float* __restrict__ bhh,
    unsigned short* __restrict__ hbuf,      // [2][64][1024] bf16
    float* __restrict__ ys,                 // [T][64][1024] fp32
    unsigned* __restrict__ flags)           // 256 x 16 uints (64B padded)
{
  extern __shared__ unsigned short Wlds[];  // 2 * 16 * 1024 bf16 = 64 KB
  const int lane = threadIdx.x;
  const int fg = blockIdx.x & 63;
  const int bg = blockIdx.x >> 6;
  const int lm = lane & 15;
  const int lq = lane >> 4;
  const int jg = fg * 16 + lm;   // this lane's feature column

  // Stage both weight slices (fp32 -> bf16), rotated-chunk layout:
  // elem off = g*16384 + r*1024 + ((c + 5*r)&127)*8 + half*4
  for (int g = 0; g < 2; ++g) {
    const float* Wsrc = (g ? Whh : Whz) + (size_t)(fg * 16) * HID;
#pragma unroll 4
    for (int it = 0; it < 64; ++it) {
      int idx = it * 64 + lane;          // 0..4095
      int r = idx >> 8, c4 = idx & 255;  // row, float4 index
      float4 v = *(const float4*)(Wsrc + (size_t)r * HID + c4 * 4);
      int c = c4 >> 1, hh = c4 & 1;
      us4 o; o[0] = f2bf(v.x); o[1] = f2bf(v.y); o[2] = f2bf(v.z); o[3] = f2bf(v.w);
      *(us4*)&Wlds[g * 16384 + r * 1024 + (((c + 5 * r) & 127) << 3) + hh * 4] = o;
    }
  }
  const float bzv = bhz[jg];
  const float bhv = bhh[jg];
  __syncthreads();

  // prefetch az/ah for t=0 (lane owns rows b = bg*16 + lq*4 + r, col jg)
  unsigned short aznx[4], ahnx[4];
  {
    const unsigned short* p = A + (size_t)(bg * 16 + lq * 4) * NC + jg;
#pragma unroll
    for (int r = 0; r < 4; ++r) { aznx[r] = p[(size_t)r * NC]; ahnx[r] = p[(size_t)r * NC + 1024]; }
  }
  float h_own[4] = {0.f, 0.f, 0.f, 0.f};

  unsigned* myflag   = &flags[blockIdx.x * 16];
  unsigned* pollflag = &flags[(bg * 64 + lane) * 16];

  for (int t = 0; t < TT; ++t) {
    f32x4 accz = {0.f, 0.f, 0.f, 0.f}, acch = {0.f, 0.f, 0.f, 0.f};

    // current-step a's; issue prefetch of t+1 early (hidden under MFMA)
    unsigned short azc[4], ahc[4];
#pragma unroll
    for (int r = 0; r < 4; ++r) { azc[r] = aznx[r]; ahc[r] = ahnx[r]; }
    if (t + 1 < TT) {
      const unsigned short* p = A + ((size_t)(t + 1) * 64 + bg * 16 + lq * 4) * NC + jg;
#pragma unroll
      for (int r = 0; r < 4; ++r) { aznx[r] = p[(size_t)r * NC]; ahnx[r] = p[(size_t)r * NC + 1024]; }
    }

    if (t > 0) {
      // ---- poll group flags (relaxed, one flag per lane, no acquire) ----
      const unsigned tv = (unsigned)t;
      unsigned v = __hip_atomic_load(pollflag, __ATOMIC_RELAXED, __HIP_MEMORY_SCOPE_AGENT);
      while (__ballot(v < tv)) {
        __builtin_amdgcn_s_sleep(1);
        v = __hip_atomic_load(pollflag, __ATOMIC_RELAXED, __HIP_MEMORY_SCOPE_AGENT);
      }
      __atomic_signal_fence(__ATOMIC_SEQ_CST);

      // ---- load h row lm (all 64 x 8B relaxed-agent loads up front) ----
      const unsigned long long* hq = (const unsigned long long*)
          (hbuf + (size_t)(t & 1) * 65536 + (size_t)(bg * 16 + lm) * HID) + lq * 2;
      unsigned long long harr[64];
#pragma unroll
      for (int kt = 0; kt < 32; ++kt) {
        harr[2 * kt]     = __hip_atomic_load(hq + kt * 8,     __ATOMIC_RELAXED, __HIP_MEMORY_SCOPE_AGENT);
        harr[2 * kt + 1] = __hip_atomic_load(hq + kt * 8 + 1, __ATOMIC_RELAXED, __HIP_MEMORY_SCOPE_AGENT);
      }
#pragma unroll
      for (int kt = 0; kt < 32; ++kt) {
        u64x2 u; u[0] = harr[2 * kt]; u[1] = harr[2 * kt + 1];
        bf16x8 afr = __builtin_bit_cast(bf16x8, u);
        int c = ((kt * 4 + lq) + 5 * lm) & 127;
        bf16x8 bz8 = ld_bf8(&Wlds[lm * 1024 + c * 8]);
        bf16x8 bh8 = ld_bf8(&Wlds[16384 + lm * 1024 + c * 8]);
        accz = __builtin_amdgcn_mfma_f32_16x16x32_bf16(afr, bz8, accz, 0, 0, 0);
        acch = __builtin_amdgcn_mfma_f32_16x16x32_bf16(afr, bh8, acch, 0, 0, 0);
      }
    }

    // ---- elementwise update; store h (t+1 buffer) via relaxed 4B stores ----
    unsigned short* hb = hbuf + (size_t)((t + 1) & 1) * 65536;
    unsigned short mybf[4];
#pragma unroll
    for (int r = 0; r < 4; ++r) {
      float z  = 1.0f / (1.0f + __expf(-(bf2f(azc[r]) + accz[r] + bzv)));
      float ht = bf2f(ahc[r]) + acch[r] + bhv;
      ht = ht > 0.f ? ht : 0.f;
      float h2 = z * h_own[r] + (1.0f - z) * ht;
      h_own[r] = h2;
      mybf[r] = f2bf(h2);
    }
#pragma unroll
    for (int r = 0; r < 4; ++r) {
      int p = __shfl((int)mybf[r], lane ^ 1, 64);
      if (!(lane & 1)) {
        unsigned w = (unsigned)mybf[r] | ((unsigned)p << 16);
        int row = bg * 16 + lq * 4 + r;
        __hip_atomic_store((unsigned*)(hb + (size_t)row * HID + jg), w,
                           __ATOMIC_RELAXED, __HIP_MEMORY_SCOPE_AGENT);
      }
    }

    // ---- signal: drain stores to coherence point, then relaxed flag ----
    __atomic_signal_fence(__ATOMIC_SEQ_CST);
    __builtin_amdgcn_s_waitcnt(0);
    __atomic_signal_fence(__ATOMIC_SEQ_CST);
    if (lane == 0)
      __hip_atomic_store(myflag, (unsigned)(t + 1), __ATOMIC_RELAXED, __HIP_MEMORY_SCOPE_AGENT);

    // ---- ys store (off critical path, normal cached stores) ----
    float* ysp = ys + ((size_t)t * 64 + bg * 16 + lq * 4) * HID + jg;
#pragma unroll
    for (int r = 0; r < 4; ++r) ysp[(size_t)r * HID] = h_own[r];
  }
}

// ---------------------------------------------------------------------------
extern "C" void kernel_launch(void* const* d_in, const int* in_sizes, int n_in,
                              void* d_out, int out_size, void* d_ws, size_t ws_size,
                              hipStream_t stream)
{
  (void)in_sizes; (void)n_in; (void)out_size; (void)ws_size;
  const float* x    = (const float*)d_in[0];
  const float* Wxz0 = (const float*)d_in[1];
  const float* gz0  = (const float*)d_in[3];
  const float* bz0  = (const float*)d_in[4];
  const float* Whz0 = (const float*)d_in[5];
  const float* bhz0 = (const float*)d_in[6];
  const float* Wxh0 = (const float*)d_in[7];
  const float* gh0  = (const float*)d_in[9];
  const float* bh0  = (const float*)d_in[10];
  const float* Whh0 = (const float*)d_in[11];
  const float* bhh0 = (const float*)d_in[12];
  const float* Wxz1 = (const float*)d_in[13];
  const float* gz1  = (const float*)d_in[15];
  const float* bz1  = (const float*)d_in[16];
  const float* Whz1 = (const float*)d_in[17];
  const float* bhz1 = (const float*)d_in[18];
  const float* Wxh1 = (const float*)d_in[19];
  const float* gh1  = (const float*)d_in[21];
  const float* bh1  = (const float*)d_in[22];
  const float* Whh1 = (const float*)d_in[23];
  const float* bhh1 = (const float*)d_in[24];

  char* ws = (char*)d_ws;
  // barrier region: layer0 flags @0 (16KB), layer1 flags @32768 (16KB)
  unsigned* flags0 = (unsigned*)(ws);
  unsigned* flags1 = (unsigned*)(ws + 32768);
  unsigned short* hbuf = (unsigned short*)(ws + 65536);          // 256 KB
  unsigned short* A    = (unsigned short*)(ws + (1 << 19));      // 131 MB
  float* ys0 = (float*)(ws + (1 << 19) + (size_t)TT * 64 * NC * 2); // 131 MB
  float* out = (float*)d_out;

  hipMemsetAsync(ws, 0, 65536, stream);

  // ---- layer 0 ----
  proj_bn_kernel<<<dim3(8000), dim3(256), 0, stream>>>(
      x, 512, Wxz0, Wxh0, gz0, bz0, gh0, bh0, A);
  {
    const unsigned short* a0 = A;
    const float* whz = Whz0; const float* vbz = bhz0;
    const float* whh = Whh0; const float* vbh = bhh0;
    unsigned short* hb = hbuf; float* yy = ys0; unsigned* ff = flags0;
    void* kargs[8] = {&a0, &whz, &vbz, &whh, &vbh, &hb, &yy, &ff};
    hipLaunchCooperativeKernel((const void*)scan_kernel, dim3(256), dim3(64),
                               kargs, 65536, stream);
  }
  // ---- layer 1 ----
  proj_bn_kernel<<<dim3(8000), dim3(256), 0, stream>>>(
      ys0, 1024, Wxz1, Wxh1, gz1, bz1, gh1, bh1, A);
  {
    const unsigned short* a0 = A;
    const float* whz = Whz1; const float* vbz = bhz1;
    const float* whh = Whh1; const float* vbh = bhh1;
    unsigned short* hb = hbuf; float* yy = out; unsigned* ff = flags1;
    void* kargs[8] = {&a0, &whz, &vbz, &whh, &vbh, &hb, &yy, &ff};
    hipLaunchCooperativeKernel((const void*)scan_kernel, dim3(256), dim3(64),
                               kargs, 65536, stream);
  }
}